// Round 13
// baseline (224.168 us; speedup 1.0000x reference)
//
#include <hip/hip_runtime.h>

typedef unsigned short u16;
typedef __attribute__((ext_vector_type(8))) short short8;
typedef __attribute__((ext_vector_type(4))) short short4v;
typedef __attribute__((ext_vector_type(4))) float f32x4;
typedef __attribute__((ext_vector_type(16))) float f32x16;

#define MFMA16(a, b, c) __builtin_amdgcn_mfma_f32_16x16x32_bf16(a, b, c, 0, 0, 0)
#define MFMA32(a, b, c) __builtin_amdgcn_mfma_f32_32x32x16_bf16(a, b, c, 0, 0, 0)

#define BB 8
#define NN 1024
#define DD 1024
#define HH 16
#define HD 64
#define MM (BB * NN)
// 0.125 (hd^-0.5) * log2(e): softmax computed in exp2 domain
#define SCLOG2 0.18033688011112042f

static __device__ __forceinline__ u16 f2bf(float f) {
  unsigned u = __float_as_uint(f);
  u += 0x7fffu + ((u >> 16) & 1u);  // RNE
  return (u16)(u >> 16);
}

static __device__ __forceinline__ void gld16(const void* g, void* l) {
  __builtin_amdgcn_global_load_lds((const __attribute__((address_space(1))) void*)g,
                                   (__attribute__((address_space(3))) void*)l, 16, 0, 0);
}

static __device__ __forceinline__ unsigned cvtpk(float lo, float hi) {
  unsigned r;
  asm("v_cvt_pk_bf16_f32 %0, %1, %2" : "=v"(r) : "v"(lo), "v"(hi));
  return r;
}

static __device__ __forceinline__ f32x16 zero16() {
  f32x16 v;
#pragma unroll
  for (int i = 0; i < 16; ++i) v[i] = 0.f;
  return v;
}

// ---- merged prep kernel: x-cast (blocks 0..4095), 4 weight casts
// (4096..6143), lens (6144) -----------------------------------------------
__global__ __launch_bounds__(256) void prep_kernel(const float* __restrict__ x,
                                                   const float* __restrict__ Wk, const float* __restrict__ Wq,
                                                   const float* __restrict__ Wv, const float* __restrict__ Wo,
                                                   u16* __restrict__ xb,
                                                   u16* __restrict__ wkb, u16* __restrict__ wqb,
                                                   u16* __restrict__ wvb, u16* __restrict__ wob,
                                                   const unsigned char* __restrict__ mask,
                                                   int* __restrict__ lens) {
  const int bid = blockIdx.x;
  const int t = threadIdx.x;
  if (bid == 6144) {  // lens
    __shared__ int acc[BB];
    if (t < BB) acc[t] = 0;
    __syncthreads();
    const bool isbyte = (mask[1] != 0);  // lengths >= 512 so element 1 is true
    for (int bb = 0; bb < BB; ++bb) {
      int s = 0;
      if (isbyte) {
        for (int i = t; i < NN; i += 256) s += mask[(size_t)bb * NN + i] ? 1 : 0;
      } else {
        const int* mi = (const int*)mask;
        for (int i = t; i < NN; i += 256) s += mi[(size_t)bb * NN + i] != 0 ? 1 : 0;
      }
      if (s) atomicAdd(&acc[bb], s);
    }
    __syncthreads();
    if (t < BB) lens[t] = acc[t];
    return;
  }
  const float* in;
  u16* out;
  int i;
  if (bid < 4096) {
    in = x; out = xb; i = bid * 256 + t;
  } else {
    const int wi = bid - 4096;
    const int mat = wi >> 9;  // 512 blocks per matrix
    switch (mat) {
      case 0: in = Wk; out = wkb; break;
      case 1: in = Wq; out = wqb; break;
      case 2: in = Wv; out = wvb; break;
      default: in = Wo; out = wob; break;
    }
    i = (wi & 511) * 256 + t;
  }
  const f32x4* p = (const f32x4*)in + (size_t)i * 2;
  const f32x4 a = p[0], b = p[1];
  short8 o;
  o[0] = (short)f2bf(a[0]); o[1] = (short)f2bf(a[1]);
  o[2] = (short)f2bf(a[2]); o[3] = (short)f2bf(a[3]);
  o[4] = (short)f2bf(b[0]); o[5] = (short)f2bf(b[1]);
  o[6] = (short)f2bf(b[2]); o[7] = (short)f2bf(b[3]);
  *(short8*)(out + (size_t)i * 8) = o;
}

// ====== DUAL GEMM core: one A-panel, TWO B-panels, TWO 128x128 outputs =====
// Same proven 2-phase skeleton (STAGE(next) before compute, one __syncthreads
// per K-step, R8-verified conflict-free swizzle byte ^= ((row>>1)&3)<<4 on
// BOTH gld16 source col and ds_read addr). NEW: 32 MFMA per barrier (2x) and
// 23 B/KFLOP ds_read intensity (per-wave 64x128 output) — register cost
// (128 AGPR + ~90 VGPR ~ 218) stays in the same <=256 occupancy bucket as the
// single version's 140 (8 waves/CU either way), LDS 48KB x 2 blocks fits.
#define STAGE_D(d, k0_)                                                             \
  _Pragma("unroll") for (int p = 0; p < 2; ++p) {                                   \
    const int off = (p * 256 + t) * 16;                                             \
    const int row = off >> 6;                                                       \
    const int colb = (off & 63) ^ (((row >> 1) & 3) << 4);                          \
    const int gofs = (k0_) + (colb >> 1);                                           \
    gld16(Ag + (size_t)(m0 + row) * 1024 + gofs, &As[d][off >> 1]);                 \
    gld16(B1g + (size_t)(n1 + row) * 1024 + gofs, &B1s[d][off >> 1]);               \
    gld16(B2g + (size_t)(n2 + row) * 1024 + gofs, &B2s[d][off >> 1]);               \
  }

#define GEMM_CORE_D()                                                           \
  STAGE_D(0, 0)                                                                 \
  __syncthreads();                                                              \
  for (int k0 = 0; k0 < 1024; k0 += 32) {                                       \
    const int cur = (k0 >> 5) & 1;                                              \
    if (k0 + 32 < 1024) { STAGE_D(cur ^ 1, k0 + 32) }                           \
    short8 af[4], b1f[4], b2f[4];                                               \
    _Pragma("unroll") for (int mi = 0; mi < 4; ++mi) {                          \
      const int row = wr * 64 + mi * 16 + li;                                   \
      const int byo = row * 64 + ((lg * 16) ^ (((row >> 1) & 3) << 4));         \
      af[mi] = *(const short8*)((const char*)&As[cur][0] + byo);                \
    }                                                                           \
    _Pragma("unroll") for (int ni = 0; ni < 4; ++ni) {                          \
      const int row = wc * 64 + ni * 16 + li;                                   \
      const int byo = row * 64 + ((lg * 16) ^ (((row >> 1) & 3) << 4));         \
      b1f[ni] = *(const short8*)((const char*)&B1s[cur][0] + byo);              \
      b2f[ni] = *(const short8*)((const char*)&B2s[cur][0] + byo);              \
    }                                                                           \
    __builtin_amdgcn_s_setprio(1);                                              \
    _Pragma("unroll") for (int mi = 0; mi < 4; ++mi)                            \
      _Pragma("unroll") for (int ni = 0; ni < 4; ++ni) {                        \
        acc1[mi][ni] = MFMA16(af[mi], b1f[ni], acc1[mi][ni]);                   \
        acc2[mi][ni] = MFMA16(af[mi], b2f[ni], acc2[mi][ni]);                   \
      }                                                                         \
    __builtin_amdgcn_s_setprio(0);                                              \
    __syncthreads();                                                            \
  }

// ---------------- fused QKV projection, dual-output blocks ------------------
// grid (MM/128, 12): y<8 -> {K,Q} pair at n=y*128 (shared A, two weights);
// y>=8 -> {V,V} at two adjacent n-tiles n=(y-8)*256, +128.
// Dead-row blocks (all 128 rows >= len) skipped entirely.
__global__ __launch_bounds__(256) void gemm_qkv(const u16* __restrict__ A,
                                                const u16* __restrict__ Wk3, const u16* __restrict__ Wq3,
                                                const u16* __restrict__ Wv3,
                                                u16* __restrict__ kb, u16* __restrict__ qb,
                                                u16* __restrict__ vtb, const int* __restrict__ lens) {
  const int m0 = blockIdx.x * 128;
  if ((m0 & 1023) >= lens[m0 >> 10]) return;  // dead rows
  __shared__ u16 As[2][4096];
  __shared__ u16 B1s[2][4096];
  __shared__ u16 B2s[2][4096];
  const int y = blockIdx.y;
  const bool kq = (y < 8);
  const u16* Ag = A;
  const u16* B1g = kq ? Wk3 : Wv3;
  const u16* B2g = kq ? Wq3 : Wv3;
  const int n1 = kq ? y * 128 : (y - 8) * 256;
  const int n2 = kq ? n1 : n1 + 128;
  const int t = threadIdx.x;
  const int lane = t & 63;
  const int w = t >> 6;
  const int wr = w >> 1, wc = w & 1;
  const int li = lane & 15, lg = lane >> 4;
  f32x4 acc1[4][4] = {};
  f32x4 acc2[4][4] = {};

  GEMM_CORE_D()

  if (kq) {
#pragma unroll
    for (int mi = 0; mi < 4; ++mi)
#pragma unroll
      for (int ni = 0; ni < 4; ++ni) {
        const int col = n1 + wc * 64 + ni * 16 + li;
        const int rowb = m0 + wr * 64 + mi * 16 + lg * 4;
#pragma unroll
        for (int r = 0; r < 4; ++r) {
          kb[(size_t)(rowb + r) * 1024 + col] = f2bf(acc1[mi][ni][r] * SCLOG2);
          qb[(size_t)(rowb + r) * 1024 + col] = f2bf(acc2[mi][ni][r]);
        }
      }
  } else {  // V: transposed per-head stores for both n-tiles
#pragma unroll
    for (int mi = 0; mi < 4; ++mi) {
      const int row = m0 + wr * 64 + mi * 16 + lg * 4;  // (b, j)
      const int bb = row >> 10, jj = row & 1023;
#pragma unroll
      for (int ni = 0; ni < 4; ++ni) {
        const int c1 = n1 + wc * 64 + ni * 16 + li;  // (h, x)
        const int c2 = n2 + wc * 64 + ni * 16 + li;
        short4v s1, s2;
#pragma unroll
        for (int r = 0; r < 4; ++r) {
          s1[r] = (short)f2bf(acc1[mi][ni][r]);
          s2[r] = (short)f2bf(acc2[mi][ni][r]);
        }
        *(short4v*)(vtb + ((size_t)((bb * HH + (c1 >> 6)) * HD + (c1 & 63))) * NN + jj) = s1;
        *(short4v*)(vtb + ((size_t)((bb * HH + (c2 >> 6)) * HD + (c2 & 63))) * NN + jj) = s2;
      }
    }
  }
}

// ---------------- output GEMM, dual-n blocks: out = attb @ Wo^T + bo --------
// grid (MM/128, 4): two adjacent 128-col tiles per block (shared A-panel).
__global__ __launch_bounds__(256) void gemm_out(const u16* __restrict__ A, const u16* __restrict__ Bw,
                                                float* __restrict__ C, const float* __restrict__ bias,
                                                const int* __restrict__ lens) {
  const int m0 = blockIdx.x * 128;
  const int n1 = blockIdx.y * 256;
  const int n2 = n1 + 128;
  const int t = threadIdx.x;
  if ((m0 & 1023) >= lens[m0 >> 10]) {  // fully-masked tile: store zeros only
    const int r = t >> 1, ch = (t & 1) * 128;
    float* Crow = C + (size_t)(m0 + r) * 1024 + n1 + ch;
    const f32x4 z = {0.f, 0.f, 0.f, 0.f};
#pragma unroll
    for (int c = 0; c < 32; ++c) *(f32x4*)(Crow + c * 4) = z;
    return;
  }
  __shared__ u16 As[2][4096];
  __shared__ u16 B1s[2][4096];
  __shared__ u16 B2s[2][4096];
  const u16* Ag = A;
  const u16* B1g = Bw;
  const u16* B2g = Bw;
  const int lane = t & 63;
  const int w = t >> 6;
  const int wr = w >> 1, wc = w & 1;
  const int li = lane & 15, lg = lane >> 4;
  f32x4 acc1[4][4] = {};
  f32x4 acc2[4][4] = {};

  GEMM_CORE_D()

#pragma unroll
  for (int ni = 0; ni < 4; ++ni) {
    const int c1 = n1 + wc * 64 + ni * 16 + li;
    const int c2 = n2 + wc * 64 + ni * 16 + li;
    const float bv1 = bias[c1];
    const float bv2 = bias[c2];
#pragma unroll
    for (int mi = 0; mi < 4; ++mi) {
      const int rowb = m0 + wr * 64 + mi * 16 + lg * 4;
#pragma unroll
      for (int r = 0; r < 4; ++r) {
        const int row = rowb + r;
        const int bb = row >> 10, ii = row & 1023;
        const bool live = ii < lens[bb];
        C[(size_t)row * 1024 + c1] = live ? (acc1[mi][ni][r] + bv1) : 0.f;
        C[(size_t)row * 1024 + c2] = live ? (acc2[mi][ni][r] + bv2) : 0.f;
      }
    }
  }
}

// ---------------- flash attention, T15 att[2] pipeline + tree reductions ----
// (unchanged from R12 — best measured)
#define QK_PART(JC, SN0_, SN1_)                                                \
  { const u16* Qc = &Qs[(JC) & 1][0];                                          \
    SN0_ = zero16(); SN1_ = zero16();                                          \
    __builtin_amdgcn_s_setprio(1);                                             \
    _Pragma("unroll") for (int ks = 0; ks < 4; ++ks) {                         \
      const short8 qf = *(const short8*)(Qc + (ks * 64 + l) * 8);              \
      SN0_ = MFMA32(qf, kf[ks], SN0_); }                                       \
    _Pragma("unroll") for (int ks = 0; ks < 4; ++ks) {                         \
      const short8 qf = *(const short8*)(Qc + ((4 + ks) * 64 + l) * 8);        \
      SN1_ = MFMA32(qf, kf[ks], SN1_); }                                       \
    __builtin_amdgcn_s_setprio(0); }

#define V_READ(JC, VF_)                                                        \
  { const u16* Vc = &Vs[(JC) & 1][0];                                          \
    _Pragma("unroll") for (int kk = 0; kk < 8; ++kk)                           \
      VF_[kk] = *(const short8*)(Vc + (kk * 64 + l) * 8); }

#define SM_PV(S0_, S1_, VF_)                                                   \
  {                                                                            \
    float tmx[8];                                                              \
    _Pragma("unroll") for (int r = 0; r < 8; ++r)                              \
      tmx[r] = fmaxf(fmaxf(S0_[r], S0_[r + 8]), fmaxf(S1_[r], S1_[r + 8]));    \
    _Pragma("unroll") for (int r = 0; r < 4; ++r)                              \
      tmx[r] = fmaxf(tmx[r], tmx[r + 4]);                                      \
    float pmax = fmaxf(fmaxf(tmx[0], tmx[1]), fmaxf(tmx[2], tmx[3]));          \
    pmax = fmaxf(pmax, __shfl_xor(pmax, 32));                                  \
    if (!__all(pmax <= m_run + 11.5f)) { /* T13 defer-max */                   \
      const float mnew = fmaxf(m_run, pmax);                                   \
      const float al = __builtin_amdgcn_exp2f(m_run - mnew);                   \
      l_run *= al;                                                             \
      _Pragma("unroll") for (int r = 0; r < 16; ++r) { o0[r] *= al; o1[r] *= al; } \
      m_run = mnew;                                                            \
    }                                                                          \
    float ac0 = 0.f, ac1 = 0.f, ac2 = 0.f, ac3 = 0.f;                          \
    _Pragma("unroll") for (int r = 0; r < 16; r += 4) {                        \
      const float p0 = __builtin_amdgcn_exp2f(S0_[r + 0] - m_run);             \
      const float p1 = __builtin_amdgcn_exp2f(S0_[r + 1] - m_run);             \
      const float p2 = __builtin_amdgcn_exp2f(S0_[r + 2] - m_run);             \
      const float p3 = __builtin_amdgcn_exp2f(S0_[r + 3] - m_run);             \
      S0_[r + 0] = p0; S0_[r + 1] = p1; S0_[r + 2] = p2; S0_[r + 3] = p3;      \
      ac0 += p0; ac1 += p1; ac2 += p2; ac3 += p3;                              \
    }                                                                          \
    _Pragma("unroll") for (int r = 0; r < 16; r += 4) {                        \
      const float p0 = __builtin_amdgcn_exp2f(S1_[r + 0] - m_run);             \
      const float p1 = __builtin_amdgcn_exp2f(S1_[r + 1] - m_run);             \
      const float p2 = __builtin_amdgcn_exp2f(S1_[r + 2] - m_run);             \
      const float p3 = __builtin_amdgcn_exp2f(S1_[r + 3] - m_run);             \
      S1_[r + 0] = p0; S1_[r + 1] = p1; S1_[r + 2] = p2; S1_[r + 3] = p3;      \
      ac0 += p0; ac1 += p1; ac2 += p2; ac3 += p3;                              \
    }                                                                          \
    float rs = (ac0 + ac1) + (ac2 + ac3);                                      \
    rs += __shfl_xor(rs, 32);                                                  \
    l_run += rs;                                                               \
    short8 pf[4];                                                              \
    _Pragma("unroll") for (int jk = 0; jk < 4; ++jk) {                         \
      const f32x16& ss = (jk < 2) ? S0_ : S1_;                                 \
      const int kk2 = jk & 1;                                                  \
      unsigned W0 = cvtpk(ss[8 * kk2 + 0], ss[8 * kk2 + 1]);                   \
      unsigned W1 = cvtpk(ss[8 * kk2 + 2], ss[8 * kk2 + 3]);                   \
      unsigned W2 = cvtpk(ss[8 * kk2 + 4], ss[8 * kk2 + 5]);                   \
      unsigned W3 = cvtpk(ss[8 * kk2 + 6], ss[8 * kk2 + 7]);                   \
      asm("v_permlane32_swap_b32 %0, %1" : "+v"(W0), "+v"(W2));                \
      asm("v_permlane32_swap_b32 %0, %1" : "+v"(W1), "+v"(W3));                \
      union { unsigned u[4]; short8 s; } pu;                                   \
      pu.u[0] = W0; pu.u[1] = W1; pu.u[2] = W2; pu.u[3] = W3;                  \
      pf[jk] = pu.s;                                                           \
    }                                                                          \
    __builtin_amdgcn_s_setprio(1);                                             \
    _Pragma("unroll") for (int kg = 0; kg < 4; ++kg) o0 = MFMA32(VF_[kg], pf[kg], o0); \
    _Pragma("unroll") for (int kg = 0; kg < 4; ++kg) o1 = MFMA32(VF_[4 + kg], pf[kg], o1); \
    __builtin_amdgcn_s_setprio(0);                                             \
  }

#define MASK_LAST(S0_, S1_)                                                    \
  { const int j0m = (nt - 1) * 64;                                             \
    if (j0m + 64 > len) {                                                      \
      _Pragma("unroll") for (int r = 0; r < 16; ++r) {                         \
        const int jl = (r & 3) + 8 * (r >> 2) + 4 * hi;                        \
        if (j0m + jl >= len) S0_[r] = -3.0e38f;                                \
        if (j0m + 32 + jl >= len) S1_[r] = -3.0e38f;                           \
      } } }

#define ATTN_BODY(JT, SP0, SP1, VFP, SN0, SN1, VFN)                            \
  { const int jc = (JT);                                                       \
    if (jc + 1 < nt) STAGE((jc + 1) & 1, (jc + 1) * 64);                       \
    QK_PART(jc, SN0, SN1)                                                      \
    SM_PV(SP0, SP1, VFP)                                                       \
    V_READ(jc, VFN)                                                            \
    __syncthreads(); }

__global__ __launch_bounds__(256) void attn_kernel(const u16* __restrict__ Kb, const u16* __restrict__ Qb,
                                                   const u16* __restrict__ Vtb, u16* __restrict__ attb,
                                                   const int* __restrict__ lens) {
  const int bid = blockIdx.x;
  const int b = bid >> 7;
  const int ic = (bid >> 3) & 7;
  const int h = ((bid & 7) << 1) | ((bid >> 6) & 1);
  const int len = lens[b];
  const int i0 = ic * 128;
  if (i0 >= len) return;  // fully-masked rows zeroed by final GEMM
  const int t = threadIdx.x;
  const int w = t >> 6, l = t & 63;
  const int l31 = l & 31, hi = l >> 5;
  const int i0w = i0 + w * 32;

  __shared__ u16 Qs[2][4096];  // 8KB per buffer
  __shared__ u16 Vs[2][4096];

  short8 kf[4];
  {
    const u16* kp = Kb + ((size_t)(b * NN + i0w + l31)) * DD + h * HD + hi * 8;
#pragma unroll
    for (int ks = 0; ks < 4; ++ks) kf[ks] = *(const short8*)(kp + ks * 16);
  }

  const size_t qsrc = ((size_t)(b * NN) + l31) * DD + h * HD + w * 16 + hi * 8;
  const size_t vsrc = ((size_t)((b * HH + h) * HD + l31)) * NN + w * 16 + hi * 8;

  auto STAGE = [&](int buf, int j0) {
    u16* qd = &Qs[buf][0] + t * 8;
    u16* vd = &Vs[buf][0] + t * 8;
    gld16(Qb + qsrc + (size_t)j0 * DD, qd);
    gld16(Qb + qsrc + (size_t)(j0 + 32) * DD, qd + 2048);
    gld16(Vtb + vsrc + j0, vd);
    gld16(Vtb + vsrc + 32 * NN + j0, vd + 2048);
  };

  f32x16 o0 = zero16(), o1 = zero16();
  float m_run = -3.0e38f, l_run = 0.f;
  const int nt = (len + 63) >> 6;  // >= 8 since len >= 512

  f32x16 sA0, sA1, sB0, sB1;
  short8 vfA[8], vfB[8];

  STAGE(0, 0);
  __syncthreads();
  if (nt > 1) STAGE(1, 64);
  QK_PART(0, sA0, sA1)
  V_READ(0, vfA)
  __syncthreads();

  int jt = 1;
  for (; jt + 1 < nt; jt += 2) {
    ATTN_BODY(jt, sA0, sA1, vfA, sB0, sB1, vfB)
    ATTN_BODY(jt + 1, sB0, sB1, vfB, sA0, sA1, vfA)
  }
  if (jt < nt) {
    ATTN_BODY(jt, sA0, sA1, vfA, sB0, sB1, vfB)
    MASK_LAST(sB0, sB1)
    SM_PV(sB0, sB1, vfB)
  } else {
    MASK_LAST(sA0, sA1)
    SM_PV(sA0, sA1, vfA)
  }

  const float inv = 1.f / l_run;
  u16* op = attb + (size_t)(b * NN + i0w + l31) * DD + h * HD + hi * 4;
#pragma unroll
  for (int xs = 0; xs < 2; ++xs) {
    const f32x16& oo = xs ? o1 : o0;
#pragma unroll
    for (int q = 0; q < 4; ++q) {
      short4v st;
#pragma unroll
      for (int e = 0; e < 4; ++e) st[e] = (short)f2bf(oo[q * 4 + e] * inv);
      *(short4v*)(op + xs * 32 + q * 8) = st;
    }
  }
}

// ---------------------------------------------------------------------------
extern "C" void kernel_launch(void* const* d_in, const int* in_sizes, int n_in,
                              void* d_out, int out_size, void* d_ws, size_t ws_size,
                              hipStream_t stream) {
  const float* x = (const float*)d_in[0];
  const unsigned char* mask = (const unsigned char*)d_in[1];
  const float* Wk = (const float*)d_in[2];
  const float* Wq = (const float*)d_in[3];
  const float* Wv = (const float*)d_in[4];
  const float* Wo = (const float*)d_in[5];
  const float* bo = (const float*)d_in[6];
  float* out = (float*)d_out;

  char* ws = (char*)d_ws;
  size_t o = 0;
  int* lens = (int*)(ws + o); o += 256;
  u16* xb  = (u16*)(ws + o); o += (size_t)MM * DD * 2;
  u16* wkb = (u16*)(ws + o); o += (size_t)DD * DD * 2;
  u16* wqb = (u16*)(ws + o); o += (size_t)DD * DD * 2;
  u16* wvb = (u16*)(ws + o); o += (size_t)DD * DD * 2;
  u16* wob = (u16*)(ws + o); o += (size_t)DD * DD * 2;
  u16* kb  = (u16*)(ws + o); o += (size_t)MM * DD * 2;
  u16* qb  = (u16*)(ws + o); o += (size_t)MM * DD * 2;
  u16* vtb = (u16*)(ws + o); o += (size_t)MM * DD * 2;
  u16* attb = xb;  // alias: x only needed until projections finish

  prep_kernel<<<dim3(6145), dim3(256), 0, stream>>>(x, Wk, Wq, Wv, Wo, xb, wkb, wqb, wvb,
                                                    wob, mask, lens);

  gemm_qkv<<<dim3(MM / 128, 12), dim3(256), 0, stream>>>(xb, wkb, wqb, wvb, kb, qb, vtb, lens);

  attn_kernel<<<dim3(1024), dim3(256), 0, stream>>>(kb, qb, vtb, attb, lens);

  gemm_out<<<dim3(MM / 128, 4), dim3(256), 0, stream>>>(attb, wob, out, bo, lens);
}

// Round 14
// 178.314 us; speedup vs baseline: 1.2572x; 1.2572x over previous
//
#include <hip/hip_runtime.h>

typedef unsigned short u16;
typedef __attribute__((ext_vector_type(8))) short short8;
typedef __attribute__((ext_vector_type(4))) short short4v;
typedef __attribute__((ext_vector_type(4))) float f32x4;
typedef __attribute__((ext_vector_type(16))) float f32x16;

#define MFMA16(a, b, c) __builtin_amdgcn_mfma_f32_16x16x32_bf16(a, b, c, 0, 0, 0)
#define MFMA32(a, b, c) __builtin_amdgcn_mfma_f32_32x32x16_bf16(a, b, c, 0, 0, 0)

#define BB 8
#define NN 1024
#define DD 1024
#define HH 16
#define HD 64
#define MM (BB * NN)
// 0.125 (hd^-0.5) * log2(e): softmax computed in exp2 domain
#define SCLOG2 0.18033688011112042f

static __device__ __forceinline__ u16 f2bf(float f) {
  unsigned u = __float_as_uint(f);
  u += 0x7fffu + ((u >> 16) & 1u);  // RNE
  return (u16)(u >> 16);
}

static __device__ __forceinline__ void gld16(const void* g, void* l) {
  __builtin_amdgcn_global_load_lds((const __attribute__((address_space(1))) void*)g,
                                   (__attribute__((address_space(3))) void*)l, 16, 0, 0);
}

static __device__ __forceinline__ unsigned cvtpk(float lo, float hi) {
  unsigned r;
  asm("v_cvt_pk_bf16_f32 %0, %1, %2" : "=v"(r) : "v"(lo), "v"(hi));
  return r;
}

static __device__ __forceinline__ f32x16 zero16() {
  f32x16 v;
#pragma unroll
  for (int i = 0; i < 16; ++i) v[i] = 0.f;
  return v;
}

// ---- merged prep kernel: x-cast (blocks 0..4095), 4 weight casts
// (4096..6143), lens (6144) -----------------------------------------------
__global__ __launch_bounds__(256) void prep_kernel(const float* __restrict__ x,
                                                   const float* __restrict__ Wk, const float* __restrict__ Wq,
                                                   const float* __restrict__ Wv, const float* __restrict__ Wo,
                                                   u16* __restrict__ xb,
                                                   u16* __restrict__ wkb, u16* __restrict__ wqb,
                                                   u16* __restrict__ wvb, u16* __restrict__ wob,
                                                   const unsigned char* __restrict__ mask,
                                                   int* __restrict__ lens) {
  const int bid = blockIdx.x;
  const int t = threadIdx.x;
  if (bid == 6144) {  // lens
    __shared__ int acc[BB];
    if (t < BB) acc[t] = 0;
    __syncthreads();
    const bool isbyte = (mask[1] != 0);  // lengths >= 512 so element 1 is true
    for (int bb = 0; bb < BB; ++bb) {
      int s = 0;
      if (isbyte) {
        for (int i = t; i < NN; i += 256) s += mask[(size_t)bb * NN + i] ? 1 : 0;
      } else {
        const int* mi = (const int*)mask;
        for (int i = t; i < NN; i += 256) s += mi[(size_t)bb * NN + i] != 0 ? 1 : 0;
      }
      if (s) atomicAdd(&acc[bb], s);
    }
    __syncthreads();
    if (t < BB) lens[t] = acc[t];
    return;
  }
  const float* in;
  u16* out;
  int i;
  if (bid < 4096) {
    in = x; out = xb; i = bid * 256 + t;
  } else {
    const int wi = bid - 4096;
    const int mat = wi >> 9;  // 512 blocks per matrix
    switch (mat) {
      case 0: in = Wk; out = wkb; break;
      case 1: in = Wq; out = wqb; break;
      case 2: in = Wv; out = wvb; break;
      default: in = Wo; out = wob; break;
    }
    i = (wi & 511) * 256 + t;
  }
  const f32x4* p = (const f32x4*)in + (size_t)i * 2;
  const f32x4 a = p[0], b = p[1];
  short8 o;
  o[0] = (short)f2bf(a[0]); o[1] = (short)f2bf(a[1]);
  o[2] = (short)f2bf(a[2]); o[3] = (short)f2bf(a[3]);
  o[4] = (short)f2bf(b[0]); o[5] = (short)f2bf(b[1]);
  o[6] = (short)f2bf(b[2]); o[7] = (short)f2bf(b[3]);
  *(short8*)(out + (size_t)i * 8) = o;
}

// ====== GEMM core: 128x128, BK=32, cross-tile dbuf, conflict-free swizzle ===
// (R9/R12 exact — best measured GEMM) byte ^= ((row>>1)&3)<<4 on BOTH gld16
// source column and ds_read addr; STAGE(next) before compute; one
// __syncthreads per K-step. Five scheduling/ILP variants (R6-R13) all land
// at or below this — 128²-structure shape plateau for K=1024 at MfmaUtil ~21%.
#define STAGE_G(d, k0_)                                                            \
  _Pragma("unroll") for (int p = 0; p < 2; ++p) {                                  \
    const int off = (p * 256 + t) * 16;                                            \
    const int row = off >> 6;                                                      \
    const int colb = (off & 63) ^ (((row >> 1) & 3) << 4);                         \
    gld16(Ag + (size_t)(m0 + row) * 1024 + (k0_) + (colb >> 1), &As[d][off >> 1]); \
    gld16(Bg + (size_t)(n0 + row) * 1024 + (k0_) + (colb >> 1), &Bs[d][off >> 1]); \
  }

#define GEMM_CORE2()                                                            \
  STAGE_G(0, 0)                                                                 \
  __syncthreads();                                                              \
  for (int k0 = 0; k0 < 1024; k0 += 32) {                                       \
    const int cur = (k0 >> 5) & 1;                                              \
    if (k0 + 32 < 1024) { STAGE_G(cur ^ 1, k0 + 32) }                           \
    short8 af[4], bf[4];                                                        \
    _Pragma("unroll") for (int mi = 0; mi < 4; ++mi) {                          \
      const int row = wr * 64 + mi * 16 + li;                                   \
      const int byo = row * 64 + ((lg * 16) ^ (((row >> 1) & 3) << 4));         \
      af[mi] = *(const short8*)((const char*)&As[cur][0] + byo);                \
    }                                                                           \
    _Pragma("unroll") for (int ni = 0; ni < 4; ++ni) {                          \
      const int row = wc * 64 + ni * 16 + li;                                   \
      const int byo = row * 64 + ((lg * 16) ^ (((row >> 1) & 3) << 4));         \
      bf[ni] = *(const short8*)((const char*)&Bs[cur][0] + byo);                \
    }                                                                           \
    __builtin_amdgcn_s_setprio(1);                                              \
    _Pragma("unroll") for (int mi = 0; mi < 4; ++mi)                            \
      _Pragma("unroll") for (int ni = 0; ni < 4; ++ni)                          \
          acc[mi][ni] = MFMA16(af[mi], bf[ni], acc[mi][ni]);                    \
    __builtin_amdgcn_s_setprio(0);                                              \
    __syncthreads();                                                            \
  }

// ---------------- fused QKV projection: C_m = xb @ W_m^T, m in {k,q,v} ------
__global__ __launch_bounds__(256) void gemm_qkv(const u16* __restrict__ A,
                                                const u16* __restrict__ Wk3, const u16* __restrict__ Wq3,
                                                const u16* __restrict__ Wv3,
                                                u16* __restrict__ kb, u16* __restrict__ qb,
                                                u16* __restrict__ vtb, const int* __restrict__ lens) {
  const int m0 = blockIdx.x * 128;
  if ((m0 & 1023) >= lens[m0 >> 10]) return;  // dead rows
  __shared__ u16 As[2][4096];
  __shared__ u16 Bs[2][4096];
  const int mat = blockIdx.y >> 3;
  const int n0 = (blockIdx.y & 7) * 128;
  const u16* Ag = A;
  const u16* Bg = (mat == 0) ? Wk3 : (mat == 1) ? Wq3 : Wv3;
  const int t = threadIdx.x;
  const int lane = t & 63;
  const int w = t >> 6;
  const int wr = w >> 1, wc = w & 1;
  const int li = lane & 15, lg = lane >> 4;
  f32x4 acc[4][4] = {};

  GEMM_CORE2()

  if (mat == 2) {  // V: transposed per-head store
#pragma unroll
    for (int mi = 0; mi < 4; ++mi) {
      const int row = m0 + wr * 64 + mi * 16 + lg * 4;  // (b, j)
      const int bb = row >> 10, jj = row & 1023;
#pragma unroll
      for (int ni = 0; ni < 4; ++ni) {
        const int col = n0 + wc * 64 + ni * 16 + li;  // (h, x)
        const int h = col >> 6, x = col & 63;
        short4v st;
#pragma unroll
        for (int r = 0; r < 4; ++r) st[r] = (short)f2bf(acc[mi][ni][r]);
        *(short4v*)(vtb + ((size_t)((bb * HH + h) * HD + x)) * NN + jj) = st;
      }
    }
  } else {
    u16* C = (mat == 0) ? kb : qb;
    const float scale = (mat == 0) ? SCLOG2 : 1.0f;
#pragma unroll
    for (int mi = 0; mi < 4; ++mi)
#pragma unroll
      for (int ni = 0; ni < 4; ++ni) {
        const int col = n0 + wc * 64 + ni * 16 + li;
        const int rowb = m0 + wr * 64 + mi * 16 + lg * 4;
#pragma unroll
        for (int r = 0; r < 4; ++r)
          C[(size_t)(rowb + r) * 1024 + col] = f2bf(acc[mi][ni][r] * scale);
      }
  }
}

// ---------------- output GEMM: out = attb @ Wo^T + bo, mask-zeroed ----------
__global__ __launch_bounds__(256) void gemm_out(const u16* __restrict__ A, const u16* __restrict__ Bw,
                                                float* __restrict__ C, const float* __restrict__ bias,
                                                const int* __restrict__ lens) {
  const int m0 = blockIdx.x * 128;
  const int n0 = blockIdx.y * 128;
  const int t = threadIdx.x;
  if ((m0 & 1023) >= lens[m0 >> 10]) {  // fully-masked tile: store zeros only
    const int r = t >> 1, ch = (t & 1) * 64;
    float* Crow = C + (size_t)(m0 + r) * 1024 + n0 + ch;
    const f32x4 z = {0.f, 0.f, 0.f, 0.f};
#pragma unroll
    for (int c = 0; c < 16; ++c) *(f32x4*)(Crow + c * 4) = z;
    return;
  }
  __shared__ u16 As[2][4096];
  __shared__ u16 Bs[2][4096];
  const u16* Ag = A;
  const u16* Bg = Bw;
  const int lane = t & 63;
  const int w = t >> 6;
  const int wr = w >> 1, wc = w & 1;
  const int li = lane & 15, lg = lane >> 4;
  f32x4 acc[4][4] = {};

  GEMM_CORE2()

#pragma unroll
  for (int ni = 0; ni < 4; ++ni) {
    const int col = n0 + wc * 64 + ni * 16 + li;
    const float bv = bias[col];
#pragma unroll
    for (int mi = 0; mi < 4; ++mi) {
      const int rowb = m0 + wr * 64 + mi * 16 + lg * 4;
#pragma unroll
      for (int r = 0; r < 4; ++r) {
        const int row = rowb + r;
        const int bb = row >> 10, ii = row & 1023;
        const float v = (ii < lens[bb]) ? (acc[mi][ni][r] + bv) : 0.f;
        C[(size_t)row * 1024 + col] = v;
      }
    }
  }
}

// ---------------- flash attention, T15 att[2] pipeline + tree reductions ----
// (R12 exact — best measured)
#define QK_PART(JC, SN0_, SN1_)                                                \
  { const u16* Qc = &Qs[(JC) & 1][0];                                          \
    SN0_ = zero16(); SN1_ = zero16();                                          \
    __builtin_amdgcn_s_setprio(1);                                             \
    _Pragma("unroll") for (int ks = 0; ks < 4; ++ks) {                         \
      const short8 qf = *(const short8*)(Qc + (ks * 64 + l) * 8);              \
      SN0_ = MFMA32(qf, kf[ks], SN0_); }                                       \
    _Pragma("unroll") for (int ks = 0; ks < 4; ++ks) {                         \
      const short8 qf = *(const short8*)(Qc + ((4 + ks) * 64 + l) * 8);        \
      SN1_ = MFMA32(qf, kf[ks], SN1_); }                                       \
    __builtin_amdgcn_s_setprio(0); }

#define V_READ(JC, VF_)                                                        \
  { const u16* Vc = &Vs[(JC) & 1][0];                                          \
    _Pragma("unroll") for (int kk = 0; kk < 8; ++kk)                           \
      VF_[kk] = *(const short8*)(Vc + (kk * 64 + l) * 8); }

#define SM_PV(S0_, S1_, VF_)                                                   \
  {                                                                            \
    float tmx[8];                                                              \
    _Pragma("unroll") for (int r = 0; r < 8; ++r)                              \
      tmx[r] = fmaxf(fmaxf(S0_[r], S0_[r + 8]), fmaxf(S1_[r], S1_[r + 8]));    \
    _Pragma("unroll") for (int r = 0; r < 4; ++r)                              \
      tmx[r] = fmaxf(tmx[r], tmx[r + 4]);                                      \
    float pmax = fmaxf(fmaxf(tmx[0], tmx[1]), fmaxf(tmx[2], tmx[3]));          \
    pmax = fmaxf(pmax, __shfl_xor(pmax, 32));                                  \
    if (!__all(pmax <= m_run + 11.5f)) { /* T13 defer-max */                   \
      const float mnew = fmaxf(m_run, pmax);                                   \
      const float al = __builtin_amdgcn_exp2f(m_run - mnew);                   \
      l_run *= al;                                                             \
      _Pragma("unroll") for (int r = 0; r < 16; ++r) { o0[r] *= al; o1[r] *= al; } \
      m_run = mnew;                                                            \
    }                                                                          \
    float ac0 = 0.f, ac1 = 0.f, ac2 = 0.f, ac3 = 0.f;                          \
    _Pragma("unroll") for (int r = 0; r < 16; r += 4) {                        \
      const float p0 = __builtin_amdgcn_exp2f(S0_[r + 0] - m_run);             \
      const float p1 = __builtin_amdgcn_exp2f(S0_[r + 1] - m_run);             \
      const float p2 = __builtin_amdgcn_exp2f(S0_[r + 2] - m_run);             \
      const float p3 = __builtin_amdgcn_exp2f(S0_[r + 3] - m_run);             \
      S0_[r + 0] = p0; S0_[r + 1] = p1; S0_[r + 2] = p2; S0_[r + 3] = p3;      \
      ac0 += p0; ac1 += p1; ac2 += p2; ac3 += p3;                              \
    }                                                                          \
    _Pragma("unroll") for (int r = 0; r < 16; r += 4) {                        \
      const float p0 = __builtin_amdgcn_exp2f(S1_[r + 0] - m_run);             \
      const float p1 = __builtin_amdgcn_exp2f(S1_[r + 1] - m_run);             \
      const float p2 = __builtin_amdgcn_exp2f(S1_[r + 2] - m_run);             \
      const float p3 = __builtin_amdgcn_exp2f(S1_[r + 3] - m_run);             \
      S1_[r + 0] = p0; S1_[r + 1] = p1; S1_[r + 2] = p2; S1_[r + 3] = p3;      \
      ac0 += p0; ac1 += p1; ac2 += p2; ac3 += p3;                              \
    }                                                                          \
    float rs = (ac0 + ac1) + (ac2 + ac3);                                      \
    rs += __shfl_xor(rs, 32);                                                  \
    l_run += rs;                                                               \
    short8 pf[4];                                                              \
    _Pragma("unroll") for (int jk = 0; jk < 4; ++jk) {                         \
      const f32x16& ss = (jk < 2) ? S0_ : S1_;                                 \
      const int kk2 = jk & 1;                                                  \
      unsigned W0 = cvtpk(ss[8 * kk2 + 0], ss[8 * kk2 + 1]);                   \
      unsigned W1 = cvtpk(ss[8 * kk2 + 2], ss[8 * kk2 + 3]);                   \
      unsigned W2 = cvtpk(ss[8 * kk2 + 4], ss[8 * kk2 + 5]);                   \
      unsigned W3 = cvtpk(ss[8 * kk2 + 6], ss[8 * kk2 + 7]);                   \
      asm("v_permlane32_swap_b32 %0, %1" : "+v"(W0), "+v"(W2));                \
      asm("v_permlane32_swap_b32 %0, %1" : "+v"(W1), "+v"(W3));                \
      union { unsigned u[4]; short8 s; } pu;                                   \
      pu.u[0] = W0; pu.u[1] = W1; pu.u[2] = W2; pu.u[3] = W3;                  \
      pf[jk] = pu.s;                                                           \
    }                                                                          \
    __builtin_amdgcn_s_setprio(1);                                             \
    _Pragma("unroll") for (int kg = 0; kg < 4; ++kg) o0 = MFMA32(VF_[kg], pf[kg], o0); \
    _Pragma("unroll") for (int kg = 0; kg < 4; ++kg) o1 = MFMA32(VF_[4 + kg], pf[kg], o1); \
    __builtin_amdgcn_s_setprio(0);                                             \
  }

#define MASK_LAST(S0_, S1_)                                                    \
  { const int j0m = (nt - 1) * 64;                                             \
    if (j0m + 64 > len) {                                                      \
      _Pragma("unroll") for (int r = 0; r < 16; ++r) {                         \
        const int jl = (r & 3) + 8 * (r >> 2) + 4 * hi;                        \
        if (j0m + jl >= len) S0_[r] = -3.0e38f;                                \
        if (j0m + 32 + jl >= len) S1_[r] = -3.0e38f;                           \
      } } }

#define ATTN_BODY(JT, SP0, SP1, VFP, SN0, SN1, VFN)                            \
  { const int jc = (JT);                                                       \
    if (jc + 1 < nt) STAGE((jc + 1) & 1, (jc + 1) * 64);                       \
    QK_PART(jc, SN0, SN1)                                                      \
    SM_PV(SP0, SP1, VFP)                                                       \
    V_READ(jc, VFN)                                                            \
    __syncthreads(); }

__global__ __launch_bounds__(256) void attn_kernel(const u16* __restrict__ Kb, const u16* __restrict__ Qb,
                                                   const u16* __restrict__ Vtb, u16* __restrict__ attb,
                                                   const int* __restrict__ lens) {
  const int bid = blockIdx.x;
  const int b = bid >> 7;
  const int ic = (bid >> 3) & 7;
  const int h = ((bid & 7) << 1) | ((bid >> 6) & 1);
  const int len = lens[b];
  const int i0 = ic * 128;
  if (i0 >= len) return;  // fully-masked rows zeroed by final GEMM
  const int t = threadIdx.x;
  const int w = t >> 6, l = t & 63;
  const int l31 = l & 31, hi = l >> 5;
  const int i0w = i0 + w * 32;

  __shared__ u16 Qs[2][4096];  // 8KB per buffer
  __shared__ u16 Vs[2][4096];

  short8 kf[4];
  {
    const u16* kp = Kb + ((size_t)(b * NN + i0w + l31)) * DD + h * HD + hi * 8;
#pragma unroll
    for (int ks = 0; ks < 4; ++ks) kf[ks] = *(const short8*)(kp + ks * 16);
  }

  const size_t qsrc = ((size_t)(b * NN) + l31) * DD + h * HD + w * 16 + hi * 8;
  const size_t vsrc = ((size_t)((b * HH + h) * HD + l31)) * NN + w * 16 + hi * 8;

  auto STAGE = [&](int buf, int j0) {
    u16* qd = &Qs[buf][0] + t * 8;
    u16* vd = &Vs[buf][0] + t * 8;
    gld16(Qb + qsrc + (size_t)j0 * DD, qd);
    gld16(Qb + qsrc + (size_t)(j0 + 32) * DD, qd + 2048);
    gld16(Vtb + vsrc + j0, vd);
    gld16(Vtb + vsrc + 32 * NN + j0, vd + 2048);
  };

  f32x16 o0 = zero16(), o1 = zero16();
  float m_run = -3.0e38f, l_run = 0.f;
  const int nt = (len + 63) >> 6;  // >= 8 since len >= 512

  f32x16 sA0, sA1, sB0, sB1;
  short8 vfA[8], vfB[8];

  STAGE(0, 0);
  __syncthreads();
  if (nt > 1) STAGE(1, 64);
  QK_PART(0, sA0, sA1)
  V_READ(0, vfA)
  __syncthreads();

  int jt = 1;
  for (; jt + 1 < nt; jt += 2) {
    ATTN_BODY(jt, sA0, sA1, vfA, sB0, sB1, vfB)
    ATTN_BODY(jt + 1, sB0, sB1, vfB, sA0, sA1, vfA)
  }
  if (jt < nt) {
    ATTN_BODY(jt, sA0, sA1, vfA, sB0, sB1, vfB)
    MASK_LAST(sB0, sB1)
    SM_PV(sB0, sB1, vfB)
  } else {
    MASK_LAST(sA0, sA1)
    SM_PV(sA0, sA1, vfA)
  }

  const float inv = 1.f / l_run;
  u16* op = attb + (size_t)(b * NN + i0w + l31) * DD + h * HD + hi * 4;
#pragma unroll
  for (int xs = 0; xs < 2; ++xs) {
    const f32x16& oo = xs ? o1 : o0;
#pragma unroll
    for (int q = 0; q < 4; ++q) {
      short4v st;
#pragma unroll
      for (int e = 0; e < 4; ++e) st[e] = (short)f2bf(oo[q * 4 + e] * inv);
      *(short4v*)(op + xs * 32 + q * 8) = st;
    }
  }
}

// ---------------------------------------------------------------------------
extern "C" void kernel_launch(void* const* d_in, const int* in_sizes, int n_in,
                              void* d_out, int out_size, void* d_ws, size_t ws_size,
                              hipStream_t stream) {
  const float* x = (const float*)d_in[0];
  const unsigned char* mask = (const unsigned char*)d_in[1];
  const float* Wk = (const float*)d_in[2];
  const float* Wq = (const float*)d_in[3];
  const float* Wv = (const float*)d_in[4];
  const float* Wo = (const float*)d_in[5];
  const float* bo = (const float*)d_in[6];
  float* out = (float*)d_out;

  char* ws = (char*)d_ws;
  size_t o = 0;
  int* lens = (int*)(ws + o); o += 256;
  u16* xb  = (u16*)(ws + o); o += (size_t)MM * DD * 2;
  u16* wkb = (u16*)(ws + o); o += (size_t)DD * DD * 2;
  u16* wqb = (u16*)(ws + o); o += (size_t)DD * DD * 2;
  u16* wvb = (u16*)(ws + o); o += (size_t)DD * DD * 2;
  u16* wob = (u16*)(ws + o); o += (size_t)DD * DD * 2;
  u16* kb  = (u16*)(ws + o); o += (size_t)MM * DD * 2;
  u16* qb  = (u16*)(ws + o); o += (size_t)MM * DD * 2;
  u16* vtb = (u16*)(ws + o); o += (size_t)MM * DD * 2;
  u16* attb = xb;  // alias: x only needed until projections finish

  prep_kernel<<<dim3(6145), dim3(256), 0, stream>>>(x, Wk, Wq, Wv, Wo, xb, wkb, wqb, wvb,
                                                    wob, mask, lens);

  gemm_qkv<<<dim3(MM / 128, 24), dim3(256), 0, stream>>>(xb, wkb, wqb, wvb, kb, qb, vtb, lens);

  attn_kernel<<<dim3(1024), dim3(256), 0, stream>>>(kb, qb, vtb, attb, lens);

  gemm_out<<<dim3(MM / 128, DD / 128), dim3(256), 0, stream>>>(attb, wob, out, bo, lens);
}

// Round 15
// 173.212 us; speedup vs baseline: 1.2942x; 1.0294x over previous
//
#include <hip/hip_runtime.h>

typedef unsigned short u16;
typedef __attribute__((ext_vector_type(8))) short short8;
typedef __attribute__((ext_vector_type(4))) short short4v;
typedef __attribute__((ext_vector_type(4))) float f32x4;
typedef __attribute__((ext_vector_type(16))) float f32x16;

#define MFMA16(a, b, c) __builtin_amdgcn_mfma_f32_16x16x32_bf16(a, b, c, 0, 0, 0)
#define MFMA32(a, b, c) __builtin_amdgcn_mfma_f32_32x32x16_bf16(a, b, c, 0, 0, 0)

#define BB 8
#define NN 1024
#define DD 1024
#define HH 16
#define HD 64
#define MM (BB * NN)
// 0.125 (hd^-0.5) * log2(e): softmax computed in exp2 domain
#define SCLOG2 0.18033688011112042f

static __device__ __forceinline__ u16 f2bf(float f) {
  unsigned u = __float_as_uint(f);
  u += 0x7fffu + ((u >> 16) & 1u);  // RNE
  return (u16)(u >> 16);
}

static __device__ __forceinline__ void gld16(const void* g, void* l) {
  __builtin_amdgcn_global_load_lds((const __attribute__((address_space(1))) void*)g,
                                   (__attribute__((address_space(3))) void*)l, 16, 0, 0);
}

static __device__ __forceinline__ unsigned cvtpk(float lo, float hi) {
  unsigned r;
  asm("v_cvt_pk_bf16_f32 %0, %1, %2" : "=v"(r) : "v"(lo), "v"(hi));
  return r;
}

static __device__ __forceinline__ f32x16 zero16() {
  f32x16 v;
#pragma unroll
  for (int i = 0; i < 16; ++i) v[i] = 0.f;
  return v;
}

// ---- merged prep kernel: x-cast (blocks 0..4095), 4 weight casts
// (4096..6143), lens (6144) -----------------------------------------------
__global__ __launch_bounds__(256) void prep_kernel(const float* __restrict__ x,
                                                   const float* __restrict__ Wk, const float* __restrict__ Wq,
                                                   const float* __restrict__ Wv, const float* __restrict__ Wo,
                                                   u16* __restrict__ xb,
                                                   u16* __restrict__ wkb, u16* __restrict__ wqb,
                                                   u16* __restrict__ wvb, u16* __restrict__ wob,
                                                   const unsigned char* __restrict__ mask,
                                                   int* __restrict__ lens) {
  const int bid = blockIdx.x;
  const int t = threadIdx.x;
  if (bid == 6144) {  // lens
    __shared__ int acc[BB];
    if (t < BB) acc[t] = 0;
    __syncthreads();
    const bool isbyte = (mask[1] != 0);  // lengths >= 512 so element 1 is true
    for (int bb = 0; bb < BB; ++bb) {
      int s = 0;
      if (isbyte) {
        for (int i = t; i < NN; i += 256) s += mask[(size_t)bb * NN + i] ? 1 : 0;
      } else {
        const int* mi = (const int*)mask;
        for (int i = t; i < NN; i += 256) s += mi[(size_t)bb * NN + i] != 0 ? 1 : 0;
      }
      if (s) atomicAdd(&acc[bb], s);
    }
    __syncthreads();
    if (t < BB) lens[t] = acc[t];
    return;
  }
  const float* in;
  u16* out;
  int i;
  if (bid < 4096) {
    in = x; out = xb; i = bid * 256 + t;
  } else {
    const int wi = bid - 4096;
    const int mat = wi >> 9;  // 512 blocks per matrix
    switch (mat) {
      case 0: in = Wk; out = wkb; break;
      case 1: in = Wq; out = wqb; break;
      case 2: in = Wv; out = wvb; break;
      default: in = Wo; out = wob; break;
    }
    i = (wi & 511) * 256 + t;
  }
  const f32x4* p = (const f32x4*)in + (size_t)i * 2;
  const f32x4 a = p[0], b = p[1];
  short8 o;
  o[0] = (short)f2bf(a[0]); o[1] = (short)f2bf(a[1]);
  o[2] = (short)f2bf(a[2]); o[3] = (short)f2bf(a[3]);
  o[4] = (short)f2bf(b[0]); o[5] = (short)f2bf(b[1]);
  o[6] = (short)f2bf(b[2]); o[7] = (short)f2bf(b[3]);
  *(short8*)(out + (size_t)i * 8) = o;
}

// ====== GEMM core: 128x128, BK=32, cross-tile dbuf, conflict-free swizzle ===
// (R9/R12 exact — best measured GEMM) byte ^= ((row>>1)&3)<<4 on BOTH gld16
// source column and ds_read addr; STAGE(next) before compute; one
// __syncthreads per K-step. Five scheduling/ILP variants (R6-R13) all land
// at or below this — 128²-structure shape plateau for K=1024 at MfmaUtil ~21%.
#define STAGE_G(d, k0_)                                                            \
  _Pragma("unroll") for (int p = 0; p < 2; ++p) {                                  \
    const int off = (p * 256 + t) * 16;                                            \
    const int row = off >> 6;                                                      \
    const int colb = (off & 63) ^ (((row >> 1) & 3) << 4);                         \
    gld16(Ag + (size_t)(m0 + row) * 1024 + (k0_) + (colb >> 1), &As[d][off >> 1]); \
    gld16(Bg + (size_t)(n0 + row) * 1024 + (k0_) + (colb >> 1), &Bs[d][off >> 1]); \
  }

#define GEMM_CORE2()                                                            \
  STAGE_G(0, 0)                                                                 \
  __syncthreads();                                                              \
  for (int k0 = 0; k0 < 1024; k0 += 32) {                                       \
    const int cur = (k0 >> 5) & 1;                                              \
    if (k0 + 32 < 1024) { STAGE_G(cur ^ 1, k0 + 32) }                           \
    short8 af[4], bf[4];                                                        \
    _Pragma("unroll") for (int mi = 0; mi < 4; ++mi) {                          \
      const int row = wr * 64 + mi * 16 + li;                                   \
      const int byo = row * 64 + ((lg * 16) ^ (((row >> 1) & 3) << 4));         \
      af[mi] = *(const short8*)((const char*)&As[cur][0] + byo);                \
    }                                                                           \
    _Pragma("unroll") for (int ni = 0; ni < 4; ++ni) {                          \
      const int row = wc * 64 + ni * 16 + li;                                   \
      const int byo = row * 64 + ((lg * 16) ^ (((row >> 1) & 3) << 4));         \
      bf[ni] = *(const short8*)((const char*)&Bs[cur][0] + byo);                \
    }                                                                           \
    __builtin_amdgcn_s_setprio(1);                                              \
    _Pragma("unroll") for (int mi = 0; mi < 4; ++mi)                            \
      _Pragma("unroll") for (int ni = 0; ni < 4; ++ni)                          \
          acc[mi][ni] = MFMA16(af[mi], bf[ni], acc[mi][ni]);                    \
    __builtin_amdgcn_s_setprio(0);                                              \
    __syncthreads();                                                            \
  }

// ---------------- fused QKV projection: C_m = xb @ W_m^T, m in {k,q,v} ------
__global__ __launch_bounds__(256) void gemm_qkv(const u16* __restrict__ A,
                                                const u16* __restrict__ Wk3, const u16* __restrict__ Wq3,
                                                const u16* __restrict__ Wv3,
                                                u16* __restrict__ kb, u16* __restrict__ qb,
                                                u16* __restrict__ vtb, const int* __restrict__ lens) {
  const int m0 = blockIdx.x * 128;
  if ((m0 & 1023) >= lens[m0 >> 10]) return;  // dead rows
  __shared__ u16 As[2][4096];
  __shared__ u16 Bs[2][4096];
  const int mat = blockIdx.y >> 3;
  const int n0 = (blockIdx.y & 7) * 128;
  const u16* Ag = A;
  const u16* Bg = (mat == 0) ? Wk3 : (mat == 1) ? Wq3 : Wv3;
  const int t = threadIdx.x;
  const int lane = t & 63;
  const int w = t >> 6;
  const int wr = w >> 1, wc = w & 1;
  const int li = lane & 15, lg = lane >> 4;
  f32x4 acc[4][4] = {};

  GEMM_CORE2()

  if (mat == 2) {  // V: transposed per-head store
#pragma unroll
    for (int mi = 0; mi < 4; ++mi) {
      const int row = m0 + wr * 64 + mi * 16 + lg * 4;  // (b, j)
      const int bb = row >> 10, jj = row & 1023;
#pragma unroll
      for (int ni = 0; ni < 4; ++ni) {
        const int col = n0 + wc * 64 + ni * 16 + li;  // (h, x)
        const int h = col >> 6, x = col & 63;
        short4v st;
#pragma unroll
        for (int r = 0; r < 4; ++r) st[r] = (short)f2bf(acc[mi][ni][r]);
        *(short4v*)(vtb + ((size_t)((bb * HH + h) * HD + x)) * NN + jj) = st;
      }
    }
  } else {
    u16* C = (mat == 0) ? kb : qb;
    const float scale = (mat == 0) ? SCLOG2 : 1.0f;
#pragma unroll
    for (int mi = 0; mi < 4; ++mi)
#pragma unroll
      for (int ni = 0; ni < 4; ++ni) {
        const int col = n0 + wc * 64 + ni * 16 + li;
        const int rowb = m0 + wr * 64 + mi * 16 + lg * 4;
#pragma unroll
        for (int r = 0; r < 4; ++r)
          C[(size_t)(rowb + r) * 1024 + col] = f2bf(acc[mi][ni][r] * scale);
      }
  }
}

// ---------------- output GEMM: out = attb @ Wo^T + bo, mask-zeroed ----------
__global__ __launch_bounds__(256) void gemm_out(const u16* __restrict__ A, const u16* __restrict__ Bw,
                                                float* __restrict__ C, const float* __restrict__ bias,
                                                const int* __restrict__ lens) {
  const int m0 = blockIdx.x * 128;
  const int n0 = blockIdx.y * 128;
  const int t = threadIdx.x;
  if ((m0 & 1023) >= lens[m0 >> 10]) {  // fully-masked tile: store zeros only
    const int r = t >> 1, ch = (t & 1) * 64;
    float* Crow = C + (size_t)(m0 + r) * 1024 + n0 + ch;
    const f32x4 z = {0.f, 0.f, 0.f, 0.f};
#pragma unroll
    for (int c = 0; c < 16; ++c) *(f32x4*)(Crow + c * 4) = z;
    return;
  }
  __shared__ u16 As[2][4096];
  __shared__ u16 Bs[2][4096];
  const u16* Ag = A;
  const u16* Bg = Bw;
  const int lane = t & 63;
  const int w = t >> 6;
  const int wr = w >> 1, wc = w & 1;
  const int li = lane & 15, lg = lane >> 4;
  f32x4 acc[4][4] = {};

  GEMM_CORE2()

#pragma unroll
  for (int ni = 0; ni < 4; ++ni) {
    const int col = n0 + wc * 64 + ni * 16 + li;
    const float bv = bias[col];
#pragma unroll
    for (int mi = 0; mi < 4; ++mi) {
      const int rowb = m0 + wr * 64 + mi * 16 + lg * 4;
#pragma unroll
      for (int r = 0; r < 4; ++r) {
        const int row = rowb + r;
        const int bb = row >> 10, ii = row & 1023;
        const float v = (ii < lens[bb]) ? (acc[mi][ni][r] + bv) : 0.f;
        C[(size_t)row * 1024 + col] = v;
      }
    }
  }
}

// ---------------- flash attention, 8 waves/block, 256 i-rows/block ----------
// R12 structure (att[2] pipeline + tree reductions) with TWO i-chunks merged
// per block: the Q/V tiles in LDS are i-independent, so 8 waves (2x the
// i-rows) share ONE staging stream — halves redundant Q/V gld16 + L2 traffic
// per i-row. Per-wave register state unchanged; STAGE = 2 gld16/thread over
// 512 threads (same tile bytes). XCD decode: bid=[b(3)|hbit(1)|ic(2)|xcd(3)]
// — 64 blocks/XCD, balanced len-mix, (b,h) groups XCD-local.
#define QK_PART(JC, SN0_, SN1_)                                                \
  { const u16* Qc = &Qs[(JC) & 1][0];                                          \
    SN0_ = zero16(); SN1_ = zero16();                                          \
    __builtin_amdgcn_s_setprio(1);                                             \
    _Pragma("unroll") for (int ks = 0; ks < 4; ++ks) {                         \
      const short8 qf = *(const short8*)(Qc + (ks * 64 + l) * 8);              \
      SN0_ = MFMA32(qf, kf[ks], SN0_); }                                       \
    _Pragma("unroll") for (int ks = 0; ks < 4; ++ks) {                         \
      const short8 qf = *(const short8*)(Qc + ((4 + ks) * 64 + l) * 8);        \
      SN1_ = MFMA32(qf, kf[ks], SN1_); }                                       \
    __builtin_amdgcn_s_setprio(0); }

#define V_READ(JC, VF_)                                                        \
  { const u16* Vc = &Vs[(JC) & 1][0];                                          \
    _Pragma("unroll") for (int kk = 0; kk < 8; ++kk)                           \
      VF_[kk] = *(const short8*)(Vc + (kk * 64 + l) * 8); }

#define SM_PV(S0_, S1_, VF_)                                                   \
  {                                                                            \
    float tmx[8];                                                              \
    _Pragma("unroll") for (int r = 0; r < 8; ++r)                              \
      tmx[r] = fmaxf(fmaxf(S0_[r], S0_[r + 8]), fmaxf(S1_[r], S1_[r + 8]));    \
    _Pragma("unroll") for (int r = 0; r < 4; ++r)                              \
      tmx[r] = fmaxf(tmx[r], tmx[r + 4]);                                      \
    float pmax = fmaxf(fmaxf(tmx[0], tmx[1]), fmaxf(tmx[2], tmx[3]));          \
    pmax = fmaxf(pmax, __shfl_xor(pmax, 32));                                  \
    if (!__all(pmax <= m_run + 11.5f)) { /* T13 defer-max */                   \
      const float mnew = fmaxf(m_run, pmax);                                   \
      const float al = __builtin_amdgcn_exp2f(m_run - mnew);                   \
      l_run *= al;                                                             \
      _Pragma("unroll") for (int r = 0; r < 16; ++r) { o0[r] *= al; o1[r] *= al; } \
      m_run = mnew;                                                            \
    }                                                                          \
    float ac0 = 0.f, ac1 = 0.f, ac2 = 0.f, ac3 = 0.f;                          \
    _Pragma("unroll") for (int r = 0; r < 16; r += 4) {                        \
      const float p0 = __builtin_amdgcn_exp2f(S0_[r + 0] - m_run);             \
      const float p1 = __builtin_amdgcn_exp2f(S0_[r + 1] - m_run);             \
      const float p2 = __builtin_amdgcn_exp2f(S0_[r + 2] - m_run);             \
      const float p3 = __builtin_amdgcn_exp2f(S0_[r + 3] - m_run);             \
      S0_[r + 0] = p0; S0_[r + 1] = p1; S0_[r + 2] = p2; S0_[r + 3] = p3;      \
      ac0 += p0; ac1 += p1; ac2 += p2; ac3 += p3;                              \
    }                                                                          \
    _Pragma("unroll") for (int r = 0; r < 16; r += 4) {                        \
      const float p0 = __builtin_amdgcn_exp2f(S1_[r + 0] - m_run);             \
      const float p1 = __builtin_amdgcn_exp2f(S1_[r + 1] - m_run);             \
      const float p2 = __builtin_amdgcn_exp2f(S1_[r + 2] - m_run);             \
      const float p3 = __builtin_amdgcn_exp2f(S1_[r + 3] - m_run);             \
      S1_[r + 0] = p0; S1_[r + 1] = p1; S1_[r + 2] = p2; S1_[r + 3] = p3;      \
      ac0 += p0; ac1 += p1; ac2 += p2; ac3 += p3;                              \
    }                                                                          \
    float rs = (ac0 + ac1) + (ac2 + ac3);                                      \
    rs += __shfl_xor(rs, 32);                                                  \
    l_run += rs;                                                               \
    short8 pf[4];                                                              \
    _Pragma("unroll") for (int jk = 0; jk < 4; ++jk) {                         \
      const f32x16& ss = (jk < 2) ? S0_ : S1_;                                 \
      const int kk2 = jk & 1;                                                  \
      unsigned W0 = cvtpk(ss[8 * kk2 + 0], ss[8 * kk2 + 1]);                   \
      unsigned W1 = cvtpk(ss[8 * kk2 + 2], ss[8 * kk2 + 3]);                   \
      unsigned W2 = cvtpk(ss[8 * kk2 + 4], ss[8 * kk2 + 5]);                   \
      unsigned W3 = cvtpk(ss[8 * kk2 + 6], ss[8 * kk2 + 7]);                   \
      asm("v_permlane32_swap_b32 %0, %1" : "+v"(W0), "+v"(W2));                \
      asm("v_permlane32_swap_b32 %0, %1" : "+v"(W1), "+v"(W3));                \
      union { unsigned u[4]; short8 s; } pu;                                   \
      pu.u[0] = W0; pu.u[1] = W1; pu.u[2] = W2; pu.u[3] = W3;                  \
      pf[jk] = pu.s;                                                           \
    }                                                                          \
    __builtin_amdgcn_s_setprio(1);                                             \
    _Pragma("unroll") for (int kg = 0; kg < 4; ++kg) o0 = MFMA32(VF_[kg], pf[kg], o0); \
    _Pragma("unroll") for (int kg = 0; kg < 4; ++kg) o1 = MFMA32(VF_[4 + kg], pf[kg], o1); \
    __builtin_amdgcn_s_setprio(0);                                             \
  }

#define MASK_LAST(S0_, S1_)                                                    \
  { const int j0m = (nt - 1) * 64;                                             \
    if (j0m + 64 > len) {                                                      \
      _Pragma("unroll") for (int r = 0; r < 16; ++r) {                         \
        const int jl = (r & 3) + 8 * (r >> 2) + 4 * hi;                        \
        if (j0m + jl >= len) S0_[r] = -3.0e38f;                                \
        if (j0m + 32 + jl >= len) S1_[r] = -3.0e38f;                           \
      } } }

#define ATTN_BODY(JT, SP0, SP1, VFP, SN0, SN1, VFN)                            \
  { const int jc = (JT);                                                       \
    if (jc + 1 < nt) STAGE((jc + 1) & 1, (jc + 1) * 64);                       \
    QK_PART(jc, SN0, SN1)                                                      \
    SM_PV(SP0, SP1, VFP)                                                       \
    V_READ(jc, VFN)                                                            \
    __syncthreads(); }

__global__ __launch_bounds__(512) void attn_kernel(const u16* __restrict__ Kb, const u16* __restrict__ Qb,
                                                   const u16* __restrict__ Vtb, u16* __restrict__ attb,
                                                   const int* __restrict__ lens) {
  const int bid = blockIdx.x;  // [b(3) | hbit(1) | ic(2) | xcd(3)]
  const int b = bid >> 6;
  const int ic = (bid >> 3) & 3;
  const int h = ((bid & 7) << 1) | ((bid >> 5) & 1);
  const int len = lens[b];
  const int i0 = ic * 256;
  if (i0 >= len) return;  // fully-masked rows zeroed by final GEMM
  const int t = threadIdx.x;
  const int w = t >> 6, l = t & 63;  // 8 waves, 32 i-rows each
  const int l31 = l & 31, hi = l >> 5;
  const int i0w = i0 + w * 32;

  __shared__ u16 Qs[2][4096];  // 8KB per buffer, shared by all 8 waves
  __shared__ u16 Vs[2][4096];

  // K fragments (B operand): col i = l31, k(hd) = ks*16 + hi*8 + e
  short8 kf[4];
  {
    const u16* kp = Kb + ((size_t)(b * NN + i0w + l31)) * DD + h * HD + hi * 8;
#pragma unroll
    for (int ks = 0; ks < 4; ++ks) kf[ks] = *(const short8*)(kp + ks * 16);
  }

  // staging: thread t fills 16B unit u=t of each tile (512 units = whole tile)
  // unit u -> (jsub=u>>8, ks=(u>>6)&3, lane=u&63): Q row j0+jsub*32+l31,
  // hd col ks*16+hi*8; V row x=jsub*32+l31, j col j0+ks*16+hi*8.
  const int ksu = (t >> 6) & 3, jsu = t >> 8;
  const size_t qsrc = ((size_t)(b * NN) + jsu * 32 + l31) * DD + h * HD + ksu * 16 + hi * 8;
  const size_t vsrc = ((size_t)((b * HH + h) * HD) + jsu * 32 + l31) * NN + ksu * 16 + hi * 8;

  auto STAGE = [&](int buf, int j0) {
    gld16(Qb + qsrc + (size_t)j0 * DD, &Qs[buf][0] + t * 8);
    gld16(Vtb + vsrc + j0, &Vs[buf][0] + t * 8);
  };

  f32x16 o0 = zero16(), o1 = zero16();
  float m_run = -3.0e38f, l_run = 0.f;
  const int nt = (len + 63) >> 6;  // >= 8 since len >= 512

  f32x16 sA0, sA1, sB0, sB1;
  short8 vfA[8], vfB[8];

  STAGE(0, 0);
  __syncthreads();
  if (nt > 1) STAGE(1, 64);
  QK_PART(0, sA0, sA1)
  V_READ(0, vfA)
  __syncthreads();

  int jt = 1;
  for (; jt + 1 < nt; jt += 2) {
    ATTN_BODY(jt, sA0, sA1, vfA, sB0, sB1, vfB)
    ATTN_BODY(jt + 1, sB0, sB1, vfB, sA0, sA1, vfA)
  }
  if (jt < nt) {
    ATTN_BODY(jt, sA0, sA1, vfA, sB0, sB1, vfB)
    MASK_LAST(sB0, sB1)
    SM_PV(sB0, sB1, vfB)
  } else {
    MASK_LAST(sA0, sA1)
    SM_PV(sA0, sA1, vfA)
  }

  const float inv = 1.f / l_run;
  u16* op = attb + (size_t)(b * NN + i0w + l31) * DD + h * HD + hi * 4;
#pragma unroll
  for (int xs = 0; xs < 2; ++xs) {
    const f32x16& oo = xs ? o1 : o0;
#pragma unroll
    for (int q = 0; q < 4; ++q) {
      short4v st;
#pragma unroll
      for (int e = 0; e < 4; ++e) st[e] = (short)f2bf(oo[q * 4 + e] * inv);
      *(short4v*)(op + xs * 32 + q * 8) = st;
    }
  }
}

// ---------------------------------------------------------------------------
extern "C" void kernel_launch(void* const* d_in, const int* in_sizes, int n_in,
                              void* d_out, int out_size, void* d_ws, size_t ws_size,
                              hipStream_t stream) {
  const float* x = (const float*)d_in[0];
  const unsigned char* mask = (const unsigned char*)d_in[1];
  const float* Wk = (const float*)d_in[2];
  const float* Wq = (const float*)d_in[3];
  const float* Wv = (const float*)d_in[4];
  const float* Wo = (const float*)d_in[5];
  const float* bo = (const float*)d_in[6];
  float* out = (float*)d_out;

  char* ws = (char*)d_ws;
  size_t o = 0;
  int* lens = (int*)(ws + o); o += 256;
  u16* xb  = (u16*)(ws + o); o += (size_t)MM * DD * 2;
  u16* wkb = (u16*)(ws + o); o += (size_t)DD * DD * 2;
  u16* wqb = (u16*)(ws + o); o += (size_t)DD * DD * 2;
  u16* wvb = (u16*)(ws + o); o += (size_t)DD * DD * 2;
  u16* wob = (u16*)(ws + o); o += (size_t)DD * DD * 2;
  u16* kb  = (u16*)(ws + o); o += (size_t)MM * DD * 2;
  u16* qb  = (u16*)(ws + o); o += (size_t)MM * DD * 2;
  u16* vtb = (u16*)(ws + o); o += (size_t)MM * DD * 2;
  u16* attb = xb;  // alias: x only needed until projections finish

  prep_kernel<<<dim3(6145), dim3(256), 0, stream>>>(x, Wk, Wq, Wv, Wo, xb, wkb, wqb, wvb,
                                                    wob, mask, lens);

  gemm_qkv<<<dim3(MM / 128, 24), dim3(256), 0, stream>>>(xb, wkb, wqb, wvb, kb, qb, vtb, lens);

  attn_kernel<<<dim3(512), dim3(512), 0, stream>>>(kb, qb, vtb, attb, lens);

  gemm_out<<<dim3(MM / 128, DD / 128), dim3(256), 0, stream>>>(attb, wob, out, bo, lens);
}